// Round 2
// baseline (1025.120 us; speedup 1.0000x reference)
//
#include <hip/hip_runtime.h>
#include <hip/hip_bf16.h>

typedef unsigned short u16;
typedef unsigned int u32;
typedef __attribute__((ext_vector_type(8))) short bf16x8;
typedef __attribute__((ext_vector_type(4))) float f32x4;
typedef __attribute__((ext_vector_type(8))) u16 u16x8;
typedef __attribute__((ext_vector_type(4))) u16 u16x4;

#define HIDDEN 2048
#define NBATCH 4
#define QLEN 2048
#define PASTLEN 2048
#define TKV 4096

__device__ __forceinline__ u16 f2b(float f) {
    u32 u = __builtin_bit_cast(u32, f);
    u += 0x7FFFu + ((u >> 16) & 1u);
    return (u16)(u >> 16);
}
__device__ __forceinline__ float b2f(u16 h) {
    u32 u = ((u32)h) << 16;
    return __builtin_bit_cast(float, u);
}

// ---------------- f32 -> bf16 convert (vectorized, 8/thread) ----------------
__global__ __launch_bounds__(256) void cvt_f32_bf16(const float* __restrict__ in,
                                                    u16* __restrict__ out, int n8) {
    int i = blockIdx.x * 256 + threadIdx.x;
    if (i >= n8) return;
    const float4* p = (const float4*)in + (size_t)i * 2;
    float4 a = p[0], b = p[1];
    u16x8 o;
    o[0] = f2b(a.x); o[1] = f2b(a.y); o[2] = f2b(a.z); o[3] = f2b(a.w);
    o[4] = f2b(b.x); o[5] = f2b(b.y); o[6] = f2b(b.z); o[7] = f2b(b.w);
    *(u16x8*)(out + (size_t)i * 8) = o;
}

// ------------- past_k/past_v -> cache region (f32) [+ bf16 copy] ------------
template<bool WB16>
__global__ __launch_bounds__(256) void past_copy(const float* __restrict__ in,
                                                 float* __restrict__ outF,
                                                 u16* __restrict__ outB) {
    size_t i4 = (size_t)blockIdx.x * 256 + threadIdx.x;   // 0 .. 4,194,303
    size_t flat = i4 * 4;
    size_t b = flat >> 22;                                 // 2048*2048 per batch
    size_t rem = flat & 4194303u;
    float4 v = *(const float4*)(in + flat);
    size_t o = b * ((size_t)TKV * HIDDEN) + rem;           // past rows = first 2048 rows
    *(float4*)(outF + o) = v;
    if (WB16) {
        u16x4 w; w[0] = f2b(v.x); w[1] = f2b(v.y); w[2] = f2b(v.z); w[3] = f2b(v.w);
        *(u16x4*)(outB + o) = w;
    }
}

// ------------- transpose V (f32 [Tkv,D]) -> V^T (bf16 [D,Tkv]) --------------
__global__ __launch_bounds__(256) void transp_v(const float* __restrict__ V,
                                                u16* __restrict__ VT) {
    const int b = blockIdx.z;
    const int d0 = blockIdx.x * 64;
    const int k0 = blockIdx.y * 64;
    const float* Vb = V + (size_t)b * TKV * HIDDEN;
    u16* Tb = VT + (size_t)b * TKV * HIDDEN;
    __shared__ u16 t[64][66];
    const int tid = threadIdx.x;
#pragma unroll
    for (int r = 0; r < 4; ++r) {
        int i = r * 256 + tid;
        int kr = i >> 4;
        int dc = (i & 15) * 4;
        float4 v = *(const float4*)&Vb[(size_t)(k0 + kr) * HIDDEN + d0 + dc];
        t[dc + 0][kr] = f2b(v.x);
        t[dc + 1][kr] = f2b(v.y);
        t[dc + 2][kr] = f2b(v.z);
        t[dc + 3][kr] = f2b(v.w);
    }
    __syncthreads();
#pragma unroll
    for (int r = 0; r < 2; ++r) {
        int i = r * 256 + tid;
        int dr = i >> 3;
        int kc = (i & 7) * 8;
        u16x8 w;
#pragma unroll
        for (int j = 0; j < 8; ++j) w[j] = t[dr][kc + j];
        *(u16x8*)&Tb[(size_t)(d0 + dr) * TKV + k0 + kc] = w;
    }
}

// ------------------- row softmax, causal bound, S -> P bf16 -----------------
template<bool SF32>
__global__ __launch_bounds__(256) void softmax_rows(const void* __restrict__ Sv,
                                                    u16* __restrict__ P) {
    const int q = blockIdx.x;
    const int b = blockIdx.y;
    const size_t roff = ((size_t)b * QLEN + q) * (size_t)TKV;
    const int L = q + (TKV - QLEN + 1);    // valid count: q + 2049
    const int tid = threadIdx.x;
    __shared__ float buf[TKV];
    __shared__ float red[8];
    float mx = -1e30f;
    if (SF32) {
        const float* S = (const float*)Sv + roff;
#pragma unroll
        for (int it = 0; it < TKV / 1024; ++it) {
            int i = it * 1024 + tid * 4;
            float4 v = *(const float4*)&S[i];
            float f0 = (i + 0 < L) ? v.x : -1e30f;
            float f1 = (i + 1 < L) ? v.y : -1e30f;
            float f2 = (i + 2 < L) ? v.z : -1e30f;
            float f3 = (i + 3 < L) ? v.w : -1e30f;
            buf[i + 0] = f0; buf[i + 1] = f1; buf[i + 2] = f2; buf[i + 3] = f3;
            mx = fmaxf(mx, fmaxf(fmaxf(f0, f1), fmaxf(f2, f3)));
        }
    } else {
        const u16* S = (const u16*)Sv + roff;
#pragma unroll
        for (int it = 0; it < TKV / 2048; ++it) {
            int i = it * 2048 + tid * 8;
            u16x8 v = *(const u16x8*)&S[i];
#pragma unroll
            for (int j = 0; j < 8; ++j) {
                float f = (i + j < L) ? b2f(v[j]) : -1e30f;
                buf[i + j] = f;
                mx = fmaxf(mx, f);
            }
        }
    }
#pragma unroll
    for (int o = 32; o > 0; o >>= 1) mx = fmaxf(mx, __shfl_xor(mx, o));
    if ((tid & 63) == 0) red[tid >> 6] = mx;
    __syncthreads();
    mx = fmaxf(fmaxf(red[0], red[1]), fmaxf(red[2], red[3]));
    float sm = 0.f;
    for (int i = tid; i < TKV; i += 256) {
        float e = __expf(buf[i] - mx);
        buf[i] = e;
        sm += e;
    }
#pragma unroll
    for (int o = 32; o > 0; o >>= 1) sm += __shfl_xor(sm, o);
    if ((tid & 63) == 0) red[4 + (tid >> 6)] = sm;
    __syncthreads();
    float inv = 1.0f / (red[4] + red[5] + red[6] + red[7]);
    u16* Pr = P + roff;
#pragma unroll
    for (int it = 0; it < TKV / 2048; ++it) {
        int i = it * 2048 + tid * 8;
        u16x8 w;
#pragma unroll
        for (int j = 0; j < 8; ++j) w[j] = f2b(buf[i + j] * inv);
        *(u16x8*)&Pr[i] = w;
    }
}

// ------------------------------ MFMA GEMM (B^T) -----------------------------
// C[m,n] = sum_k A[m,k]*B[n,k]  (both row-major along K), 128x128 tile, BK=32,
// 4 waves (2x2), 16x16x32 bf16 MFMA, double-buffered LDS via global_load_lds.
__device__ __forceinline__ void stage_tile(const u16* __restrict__ Ag,
                                           const u16* __restrict__ Bg,
                                           u16* sAbuf, u16* sBbuf, int tid, int K) {
#pragma unroll
    for (int rr = 0; rr < 2; ++rr) {
        int i = rr * 256 + tid;
        int row = i >> 2;
        int c8 = (i & 3) * 8;
        __builtin_amdgcn_global_load_lds(
            (const __attribute__((address_space(1))) void*)(Ag + (size_t)row * K + c8),
            (__attribute__((address_space(3))) void*)(sAbuf + i * 8), 16, 0, 0);
        __builtin_amdgcn_global_load_lds(
            (const __attribute__((address_space(1))) void*)(Bg + (size_t)row * K + c8),
            (__attribute__((address_space(3))) void*)(sBbuf + i * 8), 16, 0, 0);
    }
}

template<bool WF32, bool WB16, bool REMAP, bool BIAS, bool SCALE, bool SKIPDEAD, bool TRIM>
__global__ __launch_bounds__(256)
void gemm_bt(const u16* __restrict__ A, size_t aBatch,
             const u16* __restrict__ Bp, size_t bBatch,
             const float* __restrict__ bias,
             float* __restrict__ Cf, size_t cfBatch, int cfLd,
             u16* __restrict__ Cb, size_t cbBatch, int cbLd,
             int K, float scale) {
    constexpr int BMt = 128, BKt = 32;
    const int m0 = blockIdx.x * BMt;
    const int n0 = blockIdx.y * BMt;
    if (SKIPDEAD) {
        if (n0 >= m0 + BMt + PASTLEN) return;   // fully-masked causal tile
    }
    const int bz = blockIdx.z;
    const u16* Ab = A + (size_t)bz * aBatch;
    const u16* Bb = Bp + (size_t)bz * bBatch;

    __shared__ u16 sA[2][BMt * BKt];
    __shared__ u16 sB[2][BMt * BKt];

    const int tid = threadIdx.x;
    int nkt = K / BKt;
    if (TRIM) {
        int t = (m0 + BMt + PASTLEN) / BKt;     // causal K-loop trim for PV
        nkt = t < nkt ? t : nkt;
    }

    const int wid = tid >> 6;
    const int lane = tid & 63;
    const int wr = (wid >> 1) * 64;
    const int wc = (wid & 1) * 64;
    const int lr = lane & 15;
    const int kg = lane >> 4;

    f32x4 acc[4][4] = {};

    const u16* Agbase = Ab + (size_t)m0 * K;
    const u16* Bgbase = Bb + (size_t)n0 * K;

    stage_tile(Agbase, Bgbase, &sA[0][0], &sB[0][0], tid, K);
    for (int kt = 0; kt < nkt; ++kt) {
        __syncthreads();   // drains vmcnt: buf(kt) staged; all waves past compute(kt-1)
        if (kt + 1 < nkt)
            stage_tile(Agbase + (size_t)(kt + 1) * BKt, Bgbase + (size_t)(kt + 1) * BKt,
                       &sA[(kt + 1) & 1][0], &sB[(kt + 1) & 1][0], tid, K);
        const int buf = kt & 1;
        bf16x8 af[4], bfv[4];
#pragma unroll
        for (int i = 0; i < 4; ++i)
            af[i] = *(const bf16x8*)&sA[buf][(wr + i * 16 + lr) * BKt + kg * 8];
#pragma unroll
        for (int j = 0; j < 4; ++j)
            bfv[j] = *(const bf16x8*)&sB[buf][(wc + j * 16 + lr) * BKt + kg * 8];
#pragma unroll
        for (int i = 0; i < 4; ++i)
#pragma unroll
            for (int j = 0; j < 4; ++j)
                acc[i][j] = __builtin_amdgcn_mfma_f32_16x16x32_bf16(af[i], bfv[j], acc[i][j], 0, 0, 0);
    }

    // epilogue: C/D layout col=lane&15, row=(lane>>4)*4+reg  [m89-verified]
    float* Cfb = WF32 ? Cf + (size_t)bz * cfBatch : nullptr;
    u16* Cbb = WB16 ? Cb + (size_t)bz * cbBatch : nullptr;
#pragma unroll
    for (int i = 0; i < 4; ++i) {
#pragma unroll
        for (int j = 0; j < 4; ++j) {
#pragma unroll
            for (int r = 0; r < 4; ++r) {
                int m = m0 + wr + i * 16 + kg * 4 + r;
                int n = n0 + wc + j * 16 + lr;
                float v = acc[i][j][r];
                if (SCALE) v *= scale;
                if (BIAS) v += bias[n];
                size_t crow = REMAP
                    ? ((size_t)(m >> 11) * TKV + PASTLEN + (size_t)(m & (QLEN - 1)))
                    : (size_t)m;
                if (WF32) Cfb[crow * (size_t)cfLd + n] = v;
                if (WB16) Cbb[crow * (size_t)cbLd + n] = f2b(v);
            }
        }
    }
}

// --------------------------------- launcher ---------------------------------
extern "C" void kernel_launch(void* const* d_in, const int* in_sizes, int n_in,
                              void* d_out, int out_size, void* d_ws, size_t ws_size,
                              hipStream_t stream) {
    (void)in_sizes; (void)n_in; (void)out_size;
    const float* x  = (const float*)d_in[0];
    const float* pk = (const float*)d_in[1];
    const float* pv = (const float*)d_in[2];
    const float* Wq = (const float*)d_in[3];
    const float* bq = (const float*)d_in[4];
    const float* Wk = (const float*)d_in[5];
    const float* bk = (const float*)d_in[6];
    const float* Wv = (const float*)d_in[7];
    const float* bv = (const float*)d_in[8];
    const float* Wo = (const float*)d_in[9];
    const float* bo = (const float*)d_in[10];

    float* out  = (float*)d_out;
    float* outK = out + (size_t)NBATCH * QLEN * HIDDEN;     // +16,777,216
    float* outV = outK + (size_t)NBATCH * TKV * HIDDEN;     // +33,554,432

    char* ws = (char*)d_ws;
    u16* wqb = (u16*)ws;                      //  8,388,608 B
    u16* wkb = wqb + 4194304;
    u16* wvb = wkb + 4194304;
    u16* wob = wvb + 4194304;
    u16* xb  = wob + 4194304;                 // x bf16 [8192,2048]
    u16* qb  = xb + 16777216;                 // Q bf16; later ctx bf16
    u16* kb  = qb + 16777216;                 // K bf16 [B,4096,2048]; later P bf16
    u16* vt  = kb + 33554432;                 // V^T bf16 [B,2048,4096]
    void* sbuf = (void*)(vt + 33554432);      // S: f32 (134MB) or bf16 (67MB)
    const bool sf32 = ws_size >= 369098752ull;

    dim3 blk(256);

    // bf16 conversions
    cvt_f32_bf16<<<8192, blk, 0, stream>>>(x,  xb,  2097152);
    cvt_f32_bf16<<<2048, blk, 0, stream>>>(Wq, wqb, 524288);
    cvt_f32_bf16<<<2048, blk, 0, stream>>>(Wk, wkb, 524288);
    cvt_f32_bf16<<<2048, blk, 0, stream>>>(Wv, wvb, 524288);
    cvt_f32_bf16<<<2048, blk, 0, stream>>>(Wo, wob, 524288);

    // past KV -> cache outputs (+K bf16)
    past_copy<true ><<<16384, blk, 0, stream>>>(pk, outK, kb);
    past_copy<false><<<16384, blk, 0, stream>>>(pv, outV, nullptr);

    // projections: M=8192, N=2048, K=2048
    gemm_bt<false, true, false, true, false, false, false><<<dim3(64, 16, 1), blk, 0, stream>>>(
        xb, 0, wqb, 0, bq, nullptr, 0, 0, qb, 0, HIDDEN, HIDDEN, 1.f);
    gemm_bt<true, true, true, true, false, false, false><<<dim3(64, 16, 1), blk, 0, stream>>>(
        xb, 0, wkb, 0, bk, outK, 0, HIDDEN, kb, 0, HIDDEN, HIDDEN, 1.f);
    gemm_bt<true, false, true, true, false, false, false><<<dim3(64, 16, 1), blk, 0, stream>>>(
        xb, 0, wvb, 0, bv, outV, 0, HIDDEN, nullptr, 0, 0, HIDDEN, 1.f);

    // V^T for PV GEMM
    transp_v<<<dim3(32, 64, NBATCH), blk, 0, stream>>>(outV, vt);

    // scores: per batch M=2048, N=4096, K=2048, scale 1/sqrt(2048), skip dead tiles
    const float scl = 0.022097086912079608f;
    if (sf32) {
        gemm_bt<true, false, false, false, true, true, false><<<dim3(16, 32, NBATCH), blk, 0, stream>>>(
            qb, 4194304, kb, 8388608, nullptr, (float*)sbuf, 8388608, TKV, nullptr, 0, 0, HIDDEN, scl);
        softmax_rows<true><<<dim3(QLEN, NBATCH), blk, 0, stream>>>(sbuf, kb);
    } else {
        gemm_bt<false, true, false, false, true, true, false><<<dim3(16, 32, NBATCH), blk, 0, stream>>>(
            qb, 4194304, kb, 8388608, nullptr, nullptr, 0, 0, (u16*)sbuf, 8388608, TKV, HIDDEN, scl);
        softmax_rows<false><<<dim3(QLEN, NBATCH), blk, 0, stream>>>(sbuf, kb);
    }

    // PV: per batch M=2048, N=2048, K=4096 (causal-trimmed), ctx -> qb
    gemm_bt<false, true, false, false, false, false, true><<<dim3(16, 16, NBATCH), blk, 0, stream>>>(
        kb, 8388608, vt, 8388608, nullptr, nullptr, 0, 0, qb, 4194304, HIDDEN, TKV, 1.f);

    // output projection: M=8192, N=2048, K=2048 -> d_out f32
    gemm_bt<true, false, false, true, false, false, false><<<dim3(64, 16, 1), blk, 0, stream>>>(
        qb, 0, wob, 0, bo, out, 0, HIDDEN, nullptr, 0, 0, HIDDEN, 1.f);
}

// Round 3
// 754.165 us; speedup vs baseline: 1.3593x; 1.3593x over previous
//
#include <hip/hip_runtime.h>
#include <hip/hip_bf16.h>

typedef unsigned short u16;
typedef unsigned int u32;
typedef __attribute__((ext_vector_type(8))) short bf16x8;
typedef __attribute__((ext_vector_type(4))) float f32x4;
typedef __attribute__((ext_vector_type(8))) u16 u16x8;
typedef __attribute__((ext_vector_type(4))) u16 u16x4;

#define HIDDEN 2048
#define NBATCH 4
#define QLEN 2048
#define PASTLEN 2048
#define TKV 4096

#define VMCNT(n) asm volatile("s_waitcnt vmcnt(" #n ")" ::: "memory")
#define LGKM0    asm volatile("s_waitcnt lgkmcnt(0)" ::: "memory")
#define BAR      asm volatile("s_barrier" ::: "memory")
#define SCHEDB   __builtin_amdgcn_sched_barrier(0)

__device__ __forceinline__ u16 f2b(float f) {
    u32 u = __builtin_bit_cast(u32, f);
    u += 0x7FFFu + ((u >> 16) & 1u);
    return (u16)(u >> 16);
}
__device__ __forceinline__ float b2f(u16 h) {
    u32 u = ((u32)h) << 16;
    return __builtin_bit_cast(float, u);
}

// ---------------- f32 -> bf16 convert (vectorized, 8/thread) ----------------
__global__ __launch_bounds__(256) void cvt_f32_bf16(const float* __restrict__ in,
                                                    u16* __restrict__ out, int n8) {
    int i = blockIdx.x * 256 + threadIdx.x;
    if (i >= n8) return;
    const float4* p = (const float4*)in + (size_t)i * 2;
    float4 a = p[0], b = p[1];
    u16x8 o;
    o[0] = f2b(a.x); o[1] = f2b(a.y); o[2] = f2b(a.z); o[3] = f2b(a.w);
    o[4] = f2b(b.x); o[5] = f2b(b.y); o[6] = f2b(b.z); o[7] = f2b(b.w);
    *(u16x8*)(out + (size_t)i * 8) = o;
}

// ------------- past_k/past_v -> cache region (f32) [+ bf16 copy] ------------
template<bool WB16>
__global__ __launch_bounds__(256) void past_copy(const float* __restrict__ in,
                                                 float* __restrict__ outF,
                                                 u16* __restrict__ outB) {
    size_t i4 = (size_t)blockIdx.x * 256 + threadIdx.x;
    size_t flat = i4 * 4;
    size_t b = flat >> 22;
    size_t rem = flat & 4194303u;
    float4 v = *(const float4*)(in + flat);
    size_t o = b * ((size_t)TKV * HIDDEN) + rem;
    *(float4*)(outF + o) = v;
    if (WB16) {
        u16x4 w; w[0] = f2b(v.x); w[1] = f2b(v.y); w[2] = f2b(v.z); w[3] = f2b(v.w);
        *(u16x4*)(outB + o) = w;
    }
}

// ------------- transpose V (f32 [Tkv,D]) -> V^T (bf16 [D,Tkv]) --------------
__global__ __launch_bounds__(256) void transp_v(const float* __restrict__ V,
                                                u16* __restrict__ VT) {
    const int b = blockIdx.z;
    const int d0 = blockIdx.x * 64;
    const int k0 = blockIdx.y * 64;
    const float* Vb = V + (size_t)b * TKV * HIDDEN;
    u16* Tb = VT + (size_t)b * TKV * HIDDEN;
    __shared__ u16 t[64][66];
    const int tid = threadIdx.x;
#pragma unroll
    for (int r = 0; r < 4; ++r) {
        int i = r * 256 + tid;
        int kr = i >> 4;
        int dc = (i & 15) * 4;
        float4 v = *(const float4*)&Vb[(size_t)(k0 + kr) * HIDDEN + d0 + dc];
        t[dc + 0][kr] = f2b(v.x);
        t[dc + 1][kr] = f2b(v.y);
        t[dc + 2][kr] = f2b(v.z);
        t[dc + 3][kr] = f2b(v.w);
    }
    __syncthreads();
#pragma unroll
    for (int r = 0; r < 2; ++r) {
        int i = r * 256 + tid;
        int dr = i >> 3;
        int kc = (i & 7) * 8;
        u16x8 w;
#pragma unroll
        for (int j = 0; j < 8; ++j) w[j] = t[dr][kc + j];
        *(u16x8*)&Tb[(size_t)(d0 + dr) * TKV + k0 + kc] = w;
    }
}

// ------------------- row softmax, causal bound, S -> P bf16 -----------------
template<bool SF32>
__global__ __launch_bounds__(256) void softmax_rows(const void* __restrict__ Sv,
                                                    u16* __restrict__ P) {
    const int q = blockIdx.x;
    const int b = blockIdx.y;
    const size_t roff = ((size_t)b * QLEN + q) * (size_t)TKV;
    const int L = q + (TKV - QLEN + 1);
    const int tid = threadIdx.x;
    __shared__ float buf[TKV];
    __shared__ float red[8];
    float mx = -1e30f;
    if (SF32) {
        const float* S = (const float*)Sv + roff;
#pragma unroll
        for (int it = 0; it < TKV / 1024; ++it) {
            int i = it * 1024 + tid * 4;
            float4 v = *(const float4*)&S[i];
            float f0 = (i + 0 < L) ? v.x : -1e30f;
            float f1 = (i + 1 < L) ? v.y : -1e30f;
            float f2 = (i + 2 < L) ? v.z : -1e30f;
            float f3 = (i + 3 < L) ? v.w : -1e30f;
            buf[i + 0] = f0; buf[i + 1] = f1; buf[i + 2] = f2; buf[i + 3] = f3;
            mx = fmaxf(mx, fmaxf(fmaxf(f0, f1), fmaxf(f2, f3)));
        }
    } else {
        const u16* S = (const u16*)Sv + roff;
#pragma unroll
        for (int it = 0; it < TKV / 2048; ++it) {
            int i = it * 2048 + tid * 8;
            u16x8 v = *(const u16x8*)&S[i];
#pragma unroll
            for (int j = 0; j < 8; ++j) {
                float f = (i + j < L) ? b2f(v[j]) : -1e30f;
                buf[i + j] = f;
                mx = fmaxf(mx, f);
            }
        }
    }
#pragma unroll
    for (int o = 32; o > 0; o >>= 1) mx = fmaxf(mx, __shfl_xor(mx, o));
    if ((tid & 63) == 0) red[tid >> 6] = mx;
    __syncthreads();
    mx = fmaxf(fmaxf(red[0], red[1]), fmaxf(red[2], red[3]));
    float sm = 0.f;
    for (int i = tid; i < TKV; i += 256) {
        float e = __expf(buf[i] - mx);
        buf[i] = e;
        sm += e;
    }
#pragma unroll
    for (int o = 32; o > 0; o >>= 1) sm += __shfl_xor(sm, o);
    if ((tid & 63) == 0) red[4 + (tid >> 6)] = sm;
    __syncthreads();
    float inv = 1.0f / (red[4] + red[5] + red[6] + red[7]);
    u16* Pr = P + roff;
#pragma unroll
    for (int it = 0; it < TKV / 2048; ++it) {
        int i = it * 2048 + tid * 8;
        u16x8 w;
#pragma unroll
        for (int j = 0; j < 8; ++j) w[j] = f2b(buf[i + j] * inv);
        *(u16x8*)&Pr[i] = w;
    }
}

// --------------------- 256x256 8-wave pipelined MFMA GEMM -------------------
// C[m,n] = sum_k A[m,k]*B[n,k] (B^T layout). BK=32, 8 waves (2Mx4N), per-wave
// 128x64 output. 4 LDS buffers (4x32KB) = 4-deep pipeline, counted vmcnt(8)
// at tile boundaries (never 0 in steady state). LDS swizzle: involution
// byte ^= ((byte>>7)&7)<<4 (pre-swizzled global source, swizzled ds_read).
template<bool WF32, bool WB16, bool REMAP, bool BIAS, bool SCALE, bool SKIPDEAD, bool TRIM>
__global__ __launch_bounds__(512, 2)
void gemm256(const u16* __restrict__ A, size_t aBatch,
             const u16* __restrict__ Bp, size_t bBatch,
             const float* __restrict__ bias,
             float* __restrict__ Cf, size_t cfBatch, int cfLd,
             u16* __restrict__ Cb, size_t cbBatch, int cbLd,
             int K, float scale) {
    __shared__ u16 lds[4][16384];          // per buffer: A 8192 u16 | B 8192 u16

    const int nwg = gridDim.x * gridDim.y;
    int id = blockIdx.x * gridDim.y + blockIdx.y;      // x = m-tile, y = n-tile
    int swzid = (id & 7) * (nwg >> 3) + (id >> 3);     // XCD-contiguous chunks
    const int m0 = (swzid / gridDim.y) * 256;
    const int n0 = (swzid % gridDim.y) * 256;
    if (SKIPDEAD && n0 >= m0 + 256 + PASTLEN) return;  // fully-masked causal tile
    const int bz = blockIdx.z;
    const u16* Ab = A + (size_t)bz * aBatch + (size_t)m0 * K;
    const u16* Bb = Bp + (size_t)bz * bBatch + (size_t)n0 * K;

    int NT = K / 32;
    if (TRIM) { int tmax = (m0 + 256 + PASTLEN) / 32; NT = tmax < NT ? tmax : NT; }

    const int tid = threadIdx.x;
    const int wid = tid >> 6, lane = tid & 63;
    const int wr = wid >> 2, wc = wid & 3;             // 2 x 4 wave grid
    const int lrow = lane & 15, kg = lane >> 4;
    const int swz = (lrow >> 1) << 4;                  // byte-XOR for frag reads

    // staging: thread t owns 16B chunks {t, t+512} of each 16KB half.
    // LDS dest is linear (wave-uniform base + lane*16); source pre-swizzled.
    int off0 = tid << 4, off1 = (tid + 512) << 4;
    int s0 = off0 ^ (((off0 >> 7) & 7) << 4);
    int s1 = off1 ^ (((off1 >> 7) & 7) << 4);
    const u16* srcA0 = Ab + (size_t)(s0 >> 6) * K + ((s0 & 63) >> 1);
    const u16* srcA1 = Ab + (size_t)(s1 >> 6) * K + ((s1 & 63) >> 1);
    const u16* srcB0 = Bb + (size_t)(s0 >> 6) * K + ((s0 & 63) >> 1);
    const u16* srcB1 = Bb + (size_t)(s1 >> 6) * K + ((s1 & 63) >> 1);
    const int d0 = off0 >> 1, d1 = off1 >> 1;          // u16 offsets in half

#define STAGE_A(t) do { u16* _b = &lds[(t) & 3][0];                                      \
    __builtin_amdgcn_global_load_lds((const __attribute__((address_space(1))) void*)(srcA0 + (t) * 32), \
        (__attribute__((address_space(3))) void*)(_b + d0), 16, 0, 0);                   \
    __builtin_amdgcn_global_load_lds((const __attribute__((address_space(1))) void*)(srcA1 + (t) * 32), \
        (__attribute__((address_space(3))) void*)(_b + d1), 16, 0, 0); } while (0)
#define STAGE_B(t) do { u16* _b = &lds[(t) & 3][8192];                                   \
    __builtin_amdgcn_global_load_lds((const __attribute__((address_space(1))) void*)(srcB0 + (t) * 32), \
        (__attribute__((address_space(3))) void*)(_b + d0), 16, 0, 0);                   \
    __builtin_amdgcn_global_load_lds((const __attribute__((address_space(1))) void*)(srcB1 + (t) * 32), \
        (__attribute__((address_space(3))) void*)(_b + d1), 16, 0, 0); } while (0)

    // prologue: stage tiles 0,1,2 (12 loads/thread); wait oldest 4 (tile 0)
    STAGE_A(0); STAGE_B(0);
    STAGE_A(1); STAGE_B(1);
    STAGE_A(2); STAGE_B(2);
    VMCNT(8);
    BAR;

    f32x4 acc[8][4] = {};
    // frag read offsets (u16 units). XOR only touches byte bits 4-6; frag
    // strides (1024B) are bits >=10 so they add cleanly after the XOR.
    const int aoff0 = (((wr * 128 + lrow) * 64 + kg * 16) ^ swz) >> 1;
    const int boff0 = (((wc * 64 + lrow) * 64 + kg * 16) ^ swz) >> 1;

    for (int t = 0; t < NT; ++t) {
        const u16* bufA = &lds[t & 3][0];
        const u16* bufB = &lds[t & 3][8192];
        bf16x8 af[4], bfr[4];
        // ---- phase 0: rows 0-63 of wave tile ----
#pragma unroll
        for (int i = 0; i < 4; ++i) af[i] = *(const bf16x8*)&bufA[aoff0 + i * 512];
#pragma unroll
        for (int j = 0; j < 4; ++j) bfr[j] = *(const bf16x8*)&bufB[boff0 + j * 512];
        if (t + 3 < NT) STAGE_A(t + 3);
        BAR; LGKM0; SCHEDB;
        __builtin_amdgcn_s_setprio(1);
#pragma unroll
        for (int i = 0; i < 4; ++i)
#pragma unroll
            for (int j = 0; j < 4; ++j)
                acc[i][j] = __builtin_amdgcn_mfma_f32_16x16x32_bf16(af[i], bfr[j], acc[i][j], 0, 0, 0);
        __builtin_amdgcn_s_setprio(0);
        SCHEDB; BAR;
        // ---- phase 1: rows 64-127 (B frags reused) ----
#pragma unroll
        for (int i = 0; i < 4; ++i) af[i] = *(const bf16x8*)&bufA[aoff0 + (4 + i) * 512];
        if (t + 3 < NT) STAGE_B(t + 3);
        BAR; LGKM0; SCHEDB;
        __builtin_amdgcn_s_setprio(1);
#pragma unroll
        for (int i = 0; i < 4; ++i)
#pragma unroll
            for (int j = 0; j < 4; ++j)
                acc[4 + i][j] = __builtin_amdgcn_mfma_f32_16x16x32_bf16(af[i], bfr[j], acc[4 + i][j], 0, 0, 0);
        __builtin_amdgcn_s_setprio(0);
        SCHEDB;
        // tile boundary: next tile's 4 halves must be landed (all waves, via BAR)
        if (t + 3 < NT)      VMCNT(8);
        else if (t + 2 < NT) VMCNT(4);
        else if (t + 1 < NT) VMCNT(0);
        BAR;
    }
#undef STAGE_A
#undef STAGE_B

    // epilogue: C/D layout col=lane&15, row=(lane>>4)*4+reg  [m89-verified]
    float* Cfb = WF32 ? Cf + (size_t)bz * cfBatch : nullptr;
    u16* Cbb = WB16 ? Cb + (size_t)bz * cbBatch : nullptr;
#pragma unroll
    for (int i = 0; i < 8; ++i) {
#pragma unroll
        for (int j = 0; j < 4; ++j) {
#pragma unroll
            for (int r = 0; r < 4; ++r) {
                int m = m0 + wr * 128 + i * 16 + kg * 4 + r;
                int n = n0 + wc * 64 + j * 16 + lrow;
                float v = acc[i][j][r];
                if (SCALE) v *= scale;
                if (BIAS) v += bias[n];
                size_t crow = REMAP
                    ? ((size_t)(m >> 11) * TKV + PASTLEN + (size_t)(m & (QLEN - 1)))
                    : (size_t)m;
                if (WF32) Cfb[crow * (size_t)cfLd + n] = v;
                if (WB16) Cbb[crow * (size_t)cbLd + n] = f2b(v);
            }
        }
    }
}

// --------------------------------- launcher ---------------------------------
extern "C" void kernel_launch(void* const* d_in, const int* in_sizes, int n_in,
                              void* d_out, int out_size, void* d_ws, size_t ws_size,
                              hipStream_t stream) {
    (void)in_sizes; (void)n_in; (void)out_size;
    const float* x  = (const float*)d_in[0];
    const float* pk = (const float*)d_in[1];
    const float* pv = (const float*)d_in[2];
    const float* Wq = (const float*)d_in[3];
    const float* bq = (const float*)d_in[4];
    const float* Wk = (const float*)d_in[5];
    const float* bk = (const float*)d_in[6];
    const float* Wv = (const float*)d_in[7];
    const float* bv = (const float*)d_in[8];
    const float* Wo = (const float*)d_in[9];
    const float* bo = (const float*)d_in[10];

    float* out  = (float*)d_out;
    float* outK = out + (size_t)NBATCH * QLEN * HIDDEN;
    float* outV = outK + (size_t)NBATCH * TKV * HIDDEN;

    char* ws = (char*)d_ws;
    u16* wqb = (u16*)ws;
    u16* wkb = wqb + 4194304;
    u16* wvb = wkb + 4194304;
    u16* wob = wvb + 4194304;
    u16* xb  = wob + 4194304;                 // x bf16 [8192,2048]
    u16* qb  = xb + 16777216;                 // Q bf16; later ctx bf16
    u16* kb  = qb + 16777216;                 // K bf16 [B,4096,2048]; later P bf16
    u16* vt  = kb + 33554432;                 // V^T bf16 [B,2048,4096]
    void* sbuf = (void*)(vt + 33554432);      // S: f32 or bf16
    const bool sf32 = ws_size >= 369098752ull;

    dim3 blk(256);
    dim3 gblk(512);

    // bf16 conversions
    cvt_f32_bf16<<<8192, blk, 0, stream>>>(x,  xb,  2097152);
    cvt_f32_bf16<<<2048, blk, 0, stream>>>(Wq, wqb, 524288);
    cvt_f32_bf16<<<2048, blk, 0, stream>>>(Wk, wkb, 524288);
    cvt_f32_bf16<<<2048, blk, 0, stream>>>(Wv, wvb, 524288);
    cvt_f32_bf16<<<2048, blk, 0, stream>>>(Wo, wob, 524288);

    // past KV -> cache outputs (+K bf16)
    past_copy<true ><<<16384, blk, 0, stream>>>(pk, outK, kb);
    past_copy<false><<<16384, blk, 0, stream>>>(pv, outV, nullptr);

    // projections: M=8192, N=2048, K=2048 -> 32x8 tiles
    gemm256<false, true, false, true, false, false, false><<<dim3(32, 8, 1), gblk, 0, stream>>>(
        xb, 0, wqb, 0, bq, nullptr, 0, 0, qb, 0, HIDDEN, HIDDEN, 1.f);
    gemm256<true, true, true, true, false, false, false><<<dim3(32, 8, 1), gblk, 0, stream>>>(
        xb, 0, wkb, 0, bk, outK, 0, HIDDEN, kb, 0, HIDDEN, HIDDEN, 1.f);
    gemm256<true, false, true, true, false, false, false><<<dim3(32, 8, 1), gblk, 0, stream>>>(
        xb, 0, wvb, 0, bv, outV, 0, HIDDEN, nullptr, 0, 0, HIDDEN, 1.f);

    // V^T for PV GEMM
    transp_v<<<dim3(32, 64, NBATCH), blk, 0, stream>>>(outV, vt);

    // scores: per batch M=2048, N=4096, K=2048; skip dead causal tiles
    const float scl = 0.022097086912079608f;
    if (sf32) {
        gemm256<true, false, false, false, true, true, false><<<dim3(8, 16, NBATCH), gblk, 0, stream>>>(
            qb, 4194304, kb, 8388608, nullptr, (float*)sbuf, 8388608, TKV, nullptr, 0, 0, HIDDEN, scl);
        softmax_rows<true><<<dim3(QLEN, NBATCH), blk, 0, stream>>>(sbuf, kb);
    } else {
        gemm256<false, true, false, false, true, true, false><<<dim3(8, 16, NBATCH), gblk, 0, stream>>>(
            qb, 4194304, kb, 8388608, nullptr, nullptr, 0, 0, (u16*)sbuf, 8388608, TKV, HIDDEN, scl);
        softmax_rows<false><<<dim3(QLEN, NBATCH), blk, 0, stream>>>(sbuf, kb);
    }

    // PV: per batch M=2048, N=2048, K=4096 (causal-trimmed), ctx -> qb
    gemm256<false, true, false, false, false, false, true><<<dim3(8, 8, NBATCH), gblk, 0, stream>>>(
        kb, 8388608, vt, 8388608, nullptr, nullptr, 0, 0, qb, 4194304, HIDDEN, TKV, 1.f);

    // output projection: M=8192, N=2048, K=2048 -> d_out f32
    gemm256<true, false, false, true, false, false, false><<<dim3(32, 8, 1), gblk, 0, stream>>>(
        qb, 0, wob, 0, bo, out, 0, HIDDEN, nullptr, 0, 0, HIDDEN, 1.f);
}

// Round 4
// 683.590 us; speedup vs baseline: 1.4996x; 1.1032x over previous
//
#include <hip/hip_runtime.h>
#include <hip/hip_bf16.h>

typedef unsigned short u16;
typedef unsigned int u32;
typedef __attribute__((ext_vector_type(8))) short bf16x8;
typedef __attribute__((ext_vector_type(4))) float f32x4;
typedef __attribute__((ext_vector_type(8))) u16 u16x8;
typedef __attribute__((ext_vector_type(4))) u16 u16x4;

#define HIDDEN 2048
#define NBATCH 4
#define QLEN 2048
#define PASTLEN 2048
#define TKV 4096

#define VMCNT(n) asm volatile("s_waitcnt vmcnt(" #n ")" ::: "memory")
#define LGKM0    asm volatile("s_waitcnt lgkmcnt(0)" ::: "memory")
#define BAR      asm volatile("s_barrier" ::: "memory")
#define SCHEDB   __builtin_amdgcn_sched_barrier(0)

__device__ __forceinline__ u16 f2b(float f) {
    u32 u = __builtin_bit_cast(u32, f);
    u += 0x7FFFu + ((u >> 16) & 1u);
    return (u16)(u >> 16);
}
__device__ __forceinline__ float b2f(u16 h) {
    u32 u = ((u32)h) << 16;
    return __builtin_bit_cast(float, u);
}

// ------------- all f32->bf16 converts in one dispatch (dst contiguous) ------
__global__ __launch_bounds__(256) void cvt_all(const float* __restrict__ x,
                                               const float* __restrict__ wq,
                                               const float* __restrict__ wk,
                                               const float* __restrict__ wv,
                                               const float* __restrict__ wo,
                                               u16* __restrict__ dst) {
    int i8 = blockIdx.x * 256 + threadIdx.x;        // 0 .. 4194303
    const float* src;
    size_t loc;
    if (i8 < 2097152) {                              // 4 x 524288: Wq Wk Wv Wo
        int w = i8 >> 19;
        loc = (size_t)(i8 & 524287) * 8;
        src = w == 0 ? wq : w == 1 ? wk : w == 2 ? wv : wo;
    } else {                                         // x
        loc = (size_t)(i8 - 2097152) * 8;
        src = x;
    }
    const float4* p = (const float4*)(src + loc);
    float4 a = p[0], b = p[1];
    u16x8 o;
    o[0] = f2b(a.x); o[1] = f2b(a.y); o[2] = f2b(a.z); o[3] = f2b(a.w);
    o[4] = f2b(b.x); o[5] = f2b(b.y); o[6] = f2b(b.z); o[7] = f2b(b.w);
    *(u16x8*)(dst + (size_t)i8 * 8) = o;
}

// ---------- past_k + past_v -> cache outputs (f32), past_k -> kb bf16 -------
__global__ __launch_bounds__(256) void past_both(const float* __restrict__ pk,
                                                 const float* __restrict__ pv,
                                                 float* __restrict__ outK,
                                                 float* __restrict__ outV,
                                                 u16* __restrict__ kb) {
    const int bid = blockIdx.x;
    const bool isK = bid < 16384;
    size_t i4 = (size_t)(isK ? bid : bid - 16384) * 256 + threadIdx.x;
    size_t flat = i4 * 4;
    size_t b = flat >> 22;
    size_t rem = flat & 4194303u;
    size_t o = b * ((size_t)TKV * HIDDEN) + rem;
    float4 v = *(const float4*)((isK ? pk : pv) + flat);
    *(float4*)((isK ? outK : outV) + o) = v;
    if (isK) {
        u16x4 w; w[0] = f2b(v.x); w[1] = f2b(v.y); w[2] = f2b(v.z); w[3] = f2b(v.w);
        *(u16x4*)(kb + o) = w;
    }
}

// ---- transpose past_v (f32 [B,2048,2048]) -> vt[:, :, 0:2048] (bf16) -------
__global__ __launch_bounds__(256) void transp_pastv(const float* __restrict__ V,
                                                    u16* __restrict__ VT) {
    const int b = blockIdx.z;
    const int d0 = blockIdx.x * 64;
    const int k0 = blockIdx.y * 64;
    const float* Vb = V + (size_t)b * PASTLEN * HIDDEN;
    u16* Tb = VT + (size_t)b * HIDDEN * TKV;
    __shared__ u16 t[64][66];
    const int tid = threadIdx.x;
#pragma unroll
    for (int r = 0; r < 4; ++r) {
        int i = r * 256 + tid;
        int kr = i >> 4;
        int dc = (i & 15) * 4;
        float4 v = *(const float4*)&Vb[(size_t)(k0 + kr) * HIDDEN + d0 + dc];
        t[dc + 0][kr] = f2b(v.x);
        t[dc + 1][kr] = f2b(v.y);
        t[dc + 2][kr] = f2b(v.z);
        t[dc + 3][kr] = f2b(v.w);
    }
    __syncthreads();
#pragma unroll
    for (int r = 0; r < 2; ++r) {
        int i = r * 256 + tid;
        int dr = i >> 3;
        int kc = (i & 7) * 8;
        u16x8 w;
#pragma unroll
        for (int j = 0; j < 8; ++j) w[j] = t[dr][kc + j];
        *(u16x8*)&Tb[(size_t)(d0 + dr) * TKV + k0 + kc] = w;
    }
}

// ------------------- row softmax (bf16 S), causal, -> P bf16 ----------------
__global__ __launch_bounds__(256) void softmax_rows(const u16* __restrict__ S,
                                                    u16* __restrict__ P) {
    const int q = blockIdx.x;
    const int b = blockIdx.y;
    const size_t roff = ((size_t)b * QLEN + q) * (size_t)TKV;
    const int L = q + (TKV - QLEN + 1);
    const int tid = threadIdx.x;
    __shared__ float buf[TKV];
    __shared__ float red[8];
    float mx = -1e30f;
    const u16* Sr = S + roff;
#pragma unroll
    for (int it = 0; it < TKV / 2048; ++it) {
        int i = it * 2048 + tid * 8;
        u16x8 v = *(const u16x8*)&Sr[i];
#pragma unroll
        for (int j = 0; j < 8; ++j) {
            float f = (i + j < L) ? b2f(v[j]) : -1e30f;
            buf[i + j] = f;
            mx = fmaxf(mx, f);
        }
    }
#pragma unroll
    for (int o = 32; o > 0; o >>= 1) mx = fmaxf(mx, __shfl_xor(mx, o));
    if ((tid & 63) == 0) red[tid >> 6] = mx;
    __syncthreads();
    mx = fmaxf(fmaxf(red[0], red[1]), fmaxf(red[2], red[3]));
    float sm = 0.f;
    for (int i = tid; i < TKV; i += 256) {
        float e = __expf(buf[i] - mx);
        buf[i] = e;
        sm += e;
    }
#pragma unroll
    for (int o = 32; o > 0; o >>= 1) sm += __shfl_xor(sm, o);
    if ((tid & 63) == 0) red[4 + (tid >> 6)] = sm;
    __syncthreads();
    float inv = 1.0f / (red[4] + red[5] + red[6] + red[7]);
    u16* Pr = P + roff;
#pragma unroll
    for (int it = 0; it < TKV / 2048; ++it) {
        int i = it * 2048 + tid * 8;
        u16x8 w;
#pragma unroll
        for (int j = 0; j < 8; ++j) w[j] = f2b(buf[i + j] * inv);
        *(u16x8*)&Pr[i] = w;
    }
}

// --------------- shared 256x256 pipelined MFMA K-loop (8 waves) -------------
// C[m,n]=sum_k A[m,k]*B[n,k]; BK=32; 4 LDS buffers (4-deep), counted vmcnt(8);
// LDS swizzle involution byte ^= ((byte>>7)&7)<<4 (pre-swizzled global src).
__device__ __forceinline__ void kloop(const u16* __restrict__ Ab, const u16* __restrict__ Bb,
                                      int K, int NT, u16 (&lds)[4][16384], f32x4 (&acc)[8][4]) {
    const int tid = threadIdx.x;
    const int wid = tid >> 6, lane = tid & 63;
    const int wr = wid >> 2, wc = wid & 3;
    const int lrow = lane & 15, kg = lane >> 4;
    const int swz = (lrow >> 1) << 4;

    int off0 = tid << 4, off1 = (tid + 512) << 4;
    int s0 = off0 ^ (((off0 >> 7) & 7) << 4);
    int s1 = off1 ^ (((off1 >> 7) & 7) << 4);
    const u16* srcA0 = Ab + (size_t)(s0 >> 6) * K + ((s0 & 63) >> 1);
    const u16* srcA1 = Ab + (size_t)(s1 >> 6) * K + ((s1 & 63) >> 1);
    const u16* srcB0 = Bb + (size_t)(s0 >> 6) * K + ((s0 & 63) >> 1);
    const u16* srcB1 = Bb + (size_t)(s1 >> 6) * K + ((s1 & 63) >> 1);
    const int d0 = off0 >> 1, d1 = off1 >> 1;

#define STAGE_A(t) do { u16* _b = &lds[(t) & 3][0];                                      \
    __builtin_amdgcn_global_load_lds((const __attribute__((address_space(1))) void*)(srcA0 + (t) * 32), \
        (__attribute__((address_space(3))) void*)(_b + d0), 16, 0, 0);                   \
    __builtin_amdgcn_global_load_lds((const __attribute__((address_space(1))) void*)(srcA1 + (t) * 32), \
        (__attribute__((address_space(3))) void*)(_b + d1), 16, 0, 0); } while (0)
#define STAGE_B(t) do { u16* _b = &lds[(t) & 3][8192];                                   \
    __builtin_amdgcn_global_load_lds((const __attribute__((address_space(1))) void*)(srcB0 + (t) * 32), \
        (__attribute__((address_space(3))) void*)(_b + d0), 16, 0, 0);                   \
    __builtin_amdgcn_global_load_lds((const __attribute__((address_space(1))) void*)(srcB1 + (t) * 32), \
        (__attribute__((address_space(3))) void*)(_b + d1), 16, 0, 0); } while (0)

    STAGE_A(0); STAGE_B(0);
    STAGE_A(1); STAGE_B(1);
    STAGE_A(2); STAGE_B(2);
    VMCNT(8);
    BAR;

    const int aoff0 = (((wr * 128 + lrow) * 64 + kg * 16) ^ swz) >> 1;
    const int boff0 = (((wc * 64 + lrow) * 64 + kg * 16) ^ swz) >> 1;

    for (int t = 0; t < NT; ++t) {
        const u16* bufA = &lds[t & 3][0];
        const u16* bufB = &lds[t & 3][8192];
        bf16x8 af[4], bfr[4];
#pragma unroll
        for (int i = 0; i < 4; ++i) af[i] = *(const bf16x8*)&bufA[aoff0 + i * 512];
#pragma unroll
        for (int j = 0; j < 4; ++j) bfr[j] = *(const bf16x8*)&bufB[boff0 + j * 512];
        if (t + 3 < NT) STAGE_A(t + 3);
        BAR; LGKM0; SCHEDB;
        __builtin_amdgcn_s_setprio(1);
#pragma unroll
        for (int i = 0; i < 4; ++i)
#pragma unroll
            for (int j = 0; j < 4; ++j)
                acc[i][j] = __builtin_amdgcn_mfma_f32_16x16x32_bf16(af[i], bfr[j], acc[i][j], 0, 0, 0);
        __builtin_amdgcn_s_setprio(0);
        SCHEDB; BAR;
#pragma unroll
        for (int i = 0; i < 4; ++i) af[i] = *(const bf16x8*)&bufA[aoff0 + (4 + i) * 512];
        if (t + 3 < NT) STAGE_B(t + 3);
        BAR; LGKM0; SCHEDB;
        __builtin_amdgcn_s_setprio(1);
#pragma unroll
        for (int i = 0; i < 4; ++i)
#pragma unroll
            for (int j = 0; j < 4; ++j)
                acc[4 + i][j] = __builtin_amdgcn_mfma_f32_16x16x32_bf16(af[i], bfr[j], acc[4 + i][j], 0, 0, 0);
        __builtin_amdgcn_s_setprio(0);
        SCHEDB;
        if (t + 3 < NT)      VMCNT(8);
        else if (t + 2 < NT) VMCNT(4);
        else if (t + 1 < NT) VMCNT(0);
        BAR;
    }
#undef STAGE_A
#undef STAGE_B
}

// ------------------ fused QKV projection GEMM (N = 6144 concat) -------------
__global__ __launch_bounds__(512, 2)
void qkv_gemm(const u16* __restrict__ xb, const u16* __restrict__ wcat,
              const float* __restrict__ bq, const float* __restrict__ bk,
              const float* __restrict__ bv,
              u16* __restrict__ qb, float* __restrict__ outK, u16* __restrict__ kb,
              float* __restrict__ outV, u16* __restrict__ vt) {
    __shared__ u16 lds[4][16384];
    const int nwg = gridDim.x * gridDim.y;                 // 768
    const int l = blockIdx.x + gridDim.x * blockIdx.y;     // HW dispatch-linear
    const int swzid = (l & 7) * (nwg >> 3) + (l >> 3);     // XCD-contiguous m-chunks
    const int m0 = (swzid / gridDim.y) * 256;              // [0, 8192)
    const int n0 = (swzid % gridDim.y) * 256;              // [0, 6144)
    f32x4 acc[8][4] = {};
    kloop(xb + (size_t)m0 * HIDDEN, wcat + (size_t)n0 * HIDDEN, HIDDEN, HIDDEN / 32, lds, acc);

    const int tid = threadIdx.x;
    const int wid = tid >> 6, lane = tid & 63;
    const int wr = wid >> 2, wc = wid & 3;
    const int lrow = lane & 15, kg = lane >> 4;
    const int w = n0 >> 11;                                // 0=Q 1=K 2=V
    const int nn0 = n0 & 2047;
    const float* bias = w == 0 ? bq : w == 1 ? bk : bv;
    const int bb = m0 >> 11;                               // batch (256|2048)
#pragma unroll
    for (int i = 0; i < 8; ++i) {
#pragma unroll
        for (int j = 0; j < 4; ++j) {
            const int n = nn0 + wc * 64 + j * 16 + lrow;
            const int mB = m0 + wr * 128 + i * 16 + kg * 4;
            const int tokB = mB & (QLEN - 1);
            float vv[4];
#pragma unroll
            for (int r = 0; r < 4; ++r) vv[r] = acc[i][j][r] + bias[n];
            if (w == 0) {
#pragma unroll
                for (int r = 0; r < 4; ++r)
                    qb[(size_t)(mB + r) * HIDDEN + n] = f2b(vv[r]);
            } else if (w == 1) {
#pragma unroll
                for (int r = 0; r < 4; ++r) {
                    size_t crow = (size_t)bb * TKV + PASTLEN + tokB + r;
                    outK[crow * HIDDEN + n] = vv[r];
                    kb[crow * HIDDEN + n] = f2b(vv[r]);
                }
            } else {
#pragma unroll
                for (int r = 0; r < 4; ++r) {
                    size_t crow = (size_t)bb * TKV + PASTLEN + tokB + r;
                    outV[crow * HIDDEN + n] = vv[r];
                }
                u16x4 wv4;
#pragma unroll
                for (int r = 0; r < 4; ++r) wv4[r] = f2b(vv[r]);
                *(u16x4*)&vt[(size_t)bb * ((size_t)HIDDEN * TKV) +
                             (size_t)n * TKV + PASTLEN + tokB] = wv4;
            }
        }
    }
}

// -------------------- generic 256x256 GEMM (scores/PV/outproj) --------------
template<bool WF32, bool WB16, bool BIAS, bool SCALE, bool SKIPDEAD, bool TRIM, bool SWAPXY>
__global__ __launch_bounds__(512, 2)
void gemm256(const u16* __restrict__ A, size_t aBatch,
             const u16* __restrict__ Bp, size_t bBatch,
             const float* __restrict__ bias,
             float* __restrict__ Cf, int cfLd,
             u16* __restrict__ Cb, size_t cbBatch, int cbLd,
             int K, float scale) {
    __shared__ u16 lds[4][16384];
    const int nwg = gridDim.x * gridDim.y;
    const int l = blockIdx.x + gridDim.x * blockIdx.y;     // HW dispatch-linear
    const int swzid = (l & 7) * (nwg >> 3) + (l >> 3);
    const int t0 = swzid / gridDim.y, t1 = swzid % gridDim.y;
    const int m0 = (SWAPXY ? t1 : t0) * 256;
    const int n0 = (SWAPXY ? t0 : t1) * 256;
    if (SKIPDEAD && n0 >= m0 + 256 + PASTLEN) return;
    const int bz = blockIdx.z;

    int NT = K / 32;
    if (TRIM) { int tmax = (m0 + 256 + PASTLEN) / 32; NT = tmax < NT ? tmax : NT; }

    f32x4 acc[8][4] = {};
    kloop(A + (size_t)bz * aBatch + (size_t)m0 * K,
          Bp + (size_t)bz * bBatch + (size_t)n0 * K, K, NT, lds, acc);

    const int tid = threadIdx.x;
    const int wid = tid >> 6, lane = tid & 63;
    const int wr = wid >> 2, wc = wid & 3;
    const int lrow = lane & 15, kg = lane >> 4;
    float* Cfb = WF32 ? Cf : nullptr;
    u16* Cbb = WB16 ? Cb + (size_t)bz * cbBatch : nullptr;
#pragma unroll
    for (int i = 0; i < 8; ++i) {
#pragma unroll
        for (int j = 0; j < 4; ++j) {
            const int n = n0 + wc * 64 + j * 16 + lrow;
            const int mB = m0 + wr * 128 + i * 16 + kg * 4;
#pragma unroll
            for (int r = 0; r < 4; ++r) {
                float v = acc[i][j][r];
                if (SCALE) v *= scale;
                if (BIAS) v += bias[n];
                if (WF32) Cfb[(size_t)(mB + r) * cfLd + n] = v;
                if (WB16) Cbb[(size_t)(mB + r) * cbLd + n] = f2b(v);
            }
        }
    }
}

// --------------------------------- launcher ---------------------------------
extern "C" void kernel_launch(void* const* d_in, const int* in_sizes, int n_in,
                              void* d_out, int out_size, void* d_ws, size_t ws_size,
                              hipStream_t stream) {
    (void)in_sizes; (void)n_in; (void)out_size; (void)ws_size;
    const float* x  = (const float*)d_in[0];
    const float* pk = (const float*)d_in[1];
    const float* pv = (const float*)d_in[2];
    const float* Wq = (const float*)d_in[3];
    const float* bq = (const float*)d_in[4];
    const float* Wk = (const float*)d_in[5];
    const float* bk = (const float*)d_in[6];
    const float* Wv = (const float*)d_in[7];
    const float* bv = (const float*)d_in[8];
    const float* Wo = (const float*)d_in[9];
    const float* bo = (const float*)d_in[10];

    float* out  = (float*)d_out;
    float* outK = out + (size_t)NBATCH * QLEN * HIDDEN;
    float* outV = outK + (size_t)NBATCH * TKV * HIDDEN;

    char* ws = (char*)d_ws;
    u16* wqb = (u16*)ws;                      // [Wq|Wk|Wv|Wo] bf16, contiguous
    u16* wob = wqb + 3 * 4194304;
    u16* xb  = wqb + 4 * 4194304;             // x bf16 [8192,2048]
    u16* qb  = xb + 16777216;                 // Q bf16; later ctx bf16
    u16* kb  = qb + 16777216;                 // K bf16 [B,4096,2048]; later P
    u16* vt  = kb + 33554432;                 // V^T bf16 [B,2048,4096]
    u16* sbuf = vt + 33554432;                // S bf16 [B,2048,4096]

    dim3 blk(256);
    dim3 gblk(512);

    cvt_all<<<16384, blk, 0, stream>>>(x, Wq, Wk, Wv, Wo, wqb);
    past_both<<<32768, blk, 0, stream>>>(pk, pv, outK, outV, kb);
    transp_pastv<<<dim3(32, 32, NBATCH), blk, 0, stream>>>(pv, vt);

    // fused QKV projections: M=8192, N=6144, K=2048
    qkv_gemm<<<dim3(32, 24, 1), gblk, 0, stream>>>(xb, wqb, bq, bk, bv,
                                                   qb, outK, kb, outV, vt);

    // scores: per batch M=2048, N=4096, K=2048 -> S bf16; n-major XCD chunks
    const float scl = 0.022097086912079608f;
    gemm256<false, true, false, true, true, false, true><<<dim3(16, 8, NBATCH), gblk, 0, stream>>>(
        qb, 4194304, kb, 8388608, nullptr, nullptr, 0, sbuf, 8388608, TKV, HIDDEN, scl);

    softmax_rows<<<dim3(QLEN, NBATCH), blk, 0, stream>>>(sbuf, kb);

    // PV: per batch M=2048, N=2048, K=4096 (causal-trimmed) -> ctx bf16 in qb
    gemm256<false, true, false, false, false, true, false><<<dim3(8, 8, NBATCH), gblk, 0, stream>>>(
        kb, 8388608, vt, 8388608, nullptr, nullptr, 0, qb, 4194304, HIDDEN, TKV, 1.f);

    // output projection: M=8192, N=2048, K=2048 -> d_out f32
    gemm256<true, false, true, false, false, false, false><<<dim3(32, 8, 1), gblk, 0, stream>>>(
        qb, 0, wob, 0, bo, out, HIDDEN, nullptr, 0, 0, HIDDEN, 1.f);
}